// Round 1
// baseline (550.778 us; speedup 1.0000x reference)
//
#include <hip/hip_runtime.h>
#include <math.h>

#define H 32
#define KV 8
#define D 128
#define PAGE 16
#define TOPK 256
#define NPAGES 2048
#define PAST 32767
#define HID 4096

// workspace layout (float offsets)
#define WS_Q      0        // 4096
#define WS_K      4096     // 1024 (new k, rope'd)
#define WS_V      5120     // 1024 (new v)
#define WS_SCORES 6144     // 32*2048
#define WS_PIDX   71680    // 32*256 ints
#define WS_PART_M 79872    // 32*32
#define WS_PART_L 80896    // 32*32
#define WS_PART_O 81920    // 32*32*128
#define WS_ATTN   212992   // 4096

#define NCHUNK 32          // chunks per head in attention
#define PPC    8           // pages per chunk (TOPK/NCHUNK)

// ---------- 1. QKV projections: q = x@Wq, k = x@Wk, v = x@Wv ----------
// grid: 16 row-chunks x 24 col-groups (16 Wq + 4 Wk + 4 Wv), 256 thr.
// Each thread: one output column over 256 rows, atomicAdd partial.
__global__ void qkv_kernel(const float* __restrict__ x,
                           const float* __restrict__ Wq,
                           const float* __restrict__ Wk,
                           const float* __restrict__ Wv,
                           float* __restrict__ ws) {
    __shared__ float xs[256];
    int tid = threadIdx.x;
    int rc = blockIdx.x / 24;
    int cg = blockIdx.x % 24;
    int r0 = rc * 256;
    xs[tid] = x[r0 + tid];
    __syncthreads();
    const float* W; int Cc; int col; float* dst;
    if (cg < 16)      { W = Wq; Cc = 4096; col = cg * 256 + tid;        dst = ws + WS_Q + col; }
    else if (cg < 20) { W = Wk; Cc = 1024; col = (cg - 16) * 256 + tid; dst = ws + WS_K + col; }
    else              { W = Wv; Cc = 1024; col = (cg - 20) * 256 + tid; dst = ws + WS_V + col; }
    const float* Wp = W + (size_t)r0 * Cc + col;
    float acc = 0.f;
#pragma unroll 8
    for (int r = 0; r < 256; ++r)
        acc = fmaf(xs[r], Wp[(size_t)r * Cc], acc);
    atomicAdd(dst, acc);
}

// ---------- 2. RoPE on q (32 heads) and k (8 heads), pos = 32767 ----------
// one thread per (head, j) pair, j < 64, handles dims j and j+64.
// trig computed in double -> correctly-rounded fp32, to match numpy powf/cosf.
__global__ void rope_kernel(float* __restrict__ ws) {
    int idx = blockIdx.x * blockDim.x + threadIdx.x; // 0..2559
    if (idx >= 2560) return;
    float* base;
    if (idx < 2048) base = ws + WS_Q + (idx >> 6) * 128;
    else            base = ws + WS_K + ((idx - 2048) >> 6) * 128;
    int j = idx & 63;
    double t = (double)j / 64.0;
    float p = (float)pow(10000.0, t);   // CR powf
    float invf = 1.0f / p;              // fp32 divide like reference
    float ang = 32767.0f * invf;        // fp32 mul like reference
    float c = (float)cos((double)ang);  // CR cosf on the same fp32 angle
    float s = (float)sin((double)ang);
    float x0 = base[j], x1 = base[j + 64];
    base[j]      = x0 * c - x1 * s;
    base[j + 64] = x1 * c + x0 * s;
}

// ---------- 3. Page scores: per (page, kv) min/max over 16 tokens, combine with q ----------
// one wave per (page, kv); lane l covers dims 2l, 2l+1 (float2, 512B coalesced/wave).
__global__ void score_kernel(const float* __restrict__ kc,
                             const float* __restrict__ q,
                             float* __restrict__ scores) {
    int tid = threadIdx.x;
    int lane = tid & 63;
    int wv = tid >> 6;
    int p = blockIdx.x >> 1;
    int kv = ((blockIdx.x & 1) << 2) + wv;
    const float* kp = kc + ((size_t)(p * PAGE) * KV + kv) * D + 2 * lane;
    float mx0 = -INFINITY, mx1 = -INFINITY, mn0 = INFINITY, mn1 = INFINITY;
#pragma unroll
    for (int t = 0; t < PAGE; ++t) {
        float2 v = *(const float2*)(kp + (size_t)t * (KV * D));
        mx0 = fmaxf(mx0, v.x); mn0 = fminf(mn0, v.x);
        mx1 = fmaxf(mx1, v.y); mn1 = fminf(mn1, v.y);
    }
    float sacc[4];
#pragma unroll
    for (int g = 0; g < 4; ++g) {
        int h = kv * 4 + g;
        float q0 = q[h * 128 + 2 * lane];
        float q1 = q[h * 128 + 2 * lane + 1];
        sacc[g] = fmaxf(q0 * mx0, q0 * mn0) + fmaxf(q1 * mx1, q1 * mn1);
    }
#pragma unroll
    for (int off = 32; off > 0; off >>= 1) {
#pragma unroll
        for (int g = 0; g < 4; ++g) sacc[g] += __shfl_xor(sacc[g], off);
    }
    if (lane == 0) {
#pragma unroll
        for (int g = 0; g < 4; ++g)
            scores[(size_t)(kv * 4 + g) * NPAGES + p] = sacc[g];
    }
}

// ---------- 4. Exact top-256 pages per head (radix binary search on ordered uints) ----------
__global__ void topk_kernel(const float* __restrict__ scores, int* __restrict__ pidx) {
    __shared__ unsigned su[NPAGES];
    __shared__ int cnt;
    int tid = threadIdx.x;
    int h = blockIdx.x;
    for (int i = tid; i < NPAGES; i += 256) {
        unsigned u;
        if (i == NPAGES - 1) u = 0xFFFFFFFFu;   // last page forced (score=inf in ref)
        else {
            int b = __float_as_int(scores[(size_t)h * NPAGES + i]);
            u = (b >= 0) ? ((unsigned)b | 0x80000000u) : ~(unsigned)b;
        }
        su[i] = u;
    }
    __syncthreads();
    unsigned T = 0;  // max T with count(u >= T) >= TOPK  == 256th-largest value
    for (int bit = 31; bit >= 0; --bit) {
        unsigned cand = T | (1u << bit);
        if (tid == 0) cnt = 0;
        __syncthreads();
        int c = 0;
        for (int i = tid; i < NPAGES; i += 256) c += (su[i] >= cand) ? 1 : 0;
#pragma unroll
        for (int off = 32; off > 0; off >>= 1) c += __shfl_xor(c, off);
        if ((tid & 63) == 0) atomicAdd(&cnt, c);
        __syncthreads();
        if (cnt >= TOPK) T = cand;
        __syncthreads();
    }
    if (tid == 0) cnt = 0;
    __syncthreads();
    for (int i = tid; i < NPAGES; i += 256) {
        if (su[i] > T) {
            int pos = atomicAdd(&cnt, 1);
            pidx[h * TOPK + pos] = i;
        }
    }
    __syncthreads();
    if (tid == 0) {  // fill ties at threshold with lowest indices (jax tie order)
        int pos = cnt;
        for (int i = 0; i < NPAGES && pos < TOPK; ++i)
            if (su[i] == T) pidx[h * TOPK + pos++] = i;
    }
}

// ---------- 5. Sparse attention, chunked online softmax ----------
// grid: 32 heads * 32 chunks; block 256 = 4 waves; wave handles 2 pages (32 tokens),
// lane l covers dims 2l,2l+1; per-token wave butterfly for the qk dot.
__global__ void attn_kernel(const float* __restrict__ kc,
                            const float* __restrict__ vc,
                            const float* __restrict__ ws,
                            const int* __restrict__ pidx,
                            float* __restrict__ part_m,
                            float* __restrict__ part_l,
                            float* __restrict__ part_o) {
    int tid = threadIdx.x;
    int lane = tid & 63;
    int wv = tid >> 6;
    int h = blockIdx.x >> 5;
    int c = blockIdx.x & 31;
    int kvh = h >> 2;
    __shared__ float qs[128];
    __shared__ float sm[4], sl[4];
    __shared__ float so[4 * 128];
    if (tid < 128) qs[tid] = ws[WS_Q + h * 128 + tid];
    __syncthreads();
    float q0 = qs[2 * lane], q1 = qs[2 * lane + 1];
    float m = -INFINITY, l = 0.f, o0 = 0.f, o1 = 0.f;
    const float scale = 0.08838834764831843f; // fp32(1/sqrt(128))
    for (int pi = 0; pi < 2; ++pi) {
        int page = pidx[h * TOPK + c * PPC + wv * 2 + pi];
        for (int t = 0; t < PAGE; ++t) {
            int tok = page * PAGE + t;
            const float *kp, *vp;
            if (tok == PAST) { kp = ws + WS_K + kvh * 128; vp = ws + WS_V + kvh * 128; }
            else {
                size_t off = ((size_t)tok * KV + kvh) * D;
                kp = kc + off; vp = vc + off;
            }
            float2 kk = *(const float2*)(kp + 2 * lane);
            float s = q0 * kk.x + q1 * kk.y;
#pragma unroll
            for (int off2 = 32; off2 > 0; off2 >>= 1) s += __shfl_xor(s, off2);
            s *= scale;
            float2 vvv = *(const float2*)(vp + 2 * lane);
            float nm = fmaxf(m, s);
            float rs = expf(m - nm);
            float w = expf(s - nm);
            l = l * rs + w;
            o0 = o0 * rs + w * vvv.x;
            o1 = o1 * rs + w * vvv.y;
            m = nm;
        }
    }
    if (lane == 0) { sm[wv] = m; sl[wv] = l; }
    so[wv * 128 + 2 * lane]     = o0;
    so[wv * 128 + 2 * lane + 1] = o1;
    __syncthreads();
    if (tid < 128) {
        float M = fmaxf(fmaxf(sm[0], sm[1]), fmaxf(sm[2], sm[3]));
        float L = 0.f, O = 0.f;
#pragma unroll
        for (int w2 = 0; w2 < 4; ++w2) {
            float f = expf(sm[w2] - M);
            L += f * sl[w2];
            O += f * so[w2 * 128 + tid];
        }
        int pc = h * NCHUNK + c;
        if (tid == 0) { part_m[pc] = M; part_l[pc] = L; }
        part_o[(size_t)pc * 128 + tid] = O;
    }
}

// ---------- 6. Combine chunk partials -> attn_out (32 x 128) ----------
__global__ void combine_kernel(const float* __restrict__ part_m,
                               const float* __restrict__ part_l,
                               const float* __restrict__ part_o,
                               float* __restrict__ attn) {
    int h = blockIdx.x;
    int d = threadIdx.x; // 128
    float M = -INFINITY;
    for (int c = 0; c < NCHUNK; ++c) M = fmaxf(M, part_m[h * NCHUNK + c]);
    float L = 0.f, O = 0.f;
    for (int c = 0; c < NCHUNK; ++c) {
        float f = expf(part_m[h * NCHUNK + c] - M);
        L += f * part_l[h * NCHUNK + c];
        O += f * part_o[(size_t)(h * NCHUNK + c) * 128 + d];
    }
    attn[h * 128 + d] = O / L;
}

// ---------- 7. Output projection: y = attn @ Wo ----------
__global__ void wo_kernel(const float* __restrict__ attn,
                          const float* __restrict__ Wo,
                          float* __restrict__ out) {
    __shared__ float xs[256];
    int tid = threadIdx.x;
    int rc = blockIdx.x >> 4;
    int cb = blockIdx.x & 15;
    int r0 = rc * 256;
    xs[tid] = attn[r0 + tid];
    __syncthreads();
    int col = cb * 256 + tid;
    const float* Wp = Wo + (size_t)r0 * 4096 + col;
    float acc = 0.f;
#pragma unroll 8
    for (int r = 0; r < 256; ++r)
        acc = fmaf(xs[r], Wp[(size_t)r * 4096], acc);
    atomicAdd(out + col, acc);
}

extern "C" void kernel_launch(void* const* d_in, const int* in_sizes, int n_in,
                              void* d_out, int out_size, void* d_ws, size_t ws_size,
                              hipStream_t stream) {
    const float* x  = (const float*)d_in[0];
    const float* kc = (const float*)d_in[1];
    const float* vc = (const float*)d_in[2];
    const float* Wq = (const float*)d_in[3];
    const float* Wk = (const float*)d_in[4];
    const float* Wv = (const float*)d_in[5];
    const float* Wo = (const float*)d_in[6];
    float* ws = (float*)d_ws;
    float* out = (float*)d_out;

    // zero atomic accumulators (ws is poisoned 0xAA every call) + output
    hipMemsetAsync(ws, 0, 6144 * sizeof(float), stream);
    hipMemsetAsync(out, 0, (size_t)out_size * sizeof(float), stream);

    qkv_kernel<<<384, 256, 0, stream>>>(x, Wq, Wk, Wv, ws);
    rope_kernel<<<10, 256, 0, stream>>>(ws);
    score_kernel<<<(NPAGES - 1) * 2, 256, 0, stream>>>(kc, ws + WS_Q, ws + WS_SCORES);
    topk_kernel<<<H, 256, 0, stream>>>(ws + WS_SCORES, (int*)(ws + WS_PIDX));
    attn_kernel<<<H * NCHUNK, 256, 0, stream>>>(kc, vc, ws, (const int*)(ws + WS_PIDX),
                                                ws + WS_PART_M, ws + WS_PART_L, ws + WS_PART_O);
    combine_kernel<<<H, 128, 0, stream>>>(ws + WS_PART_M, ws + WS_PART_L, ws + WS_PART_O,
                                          ws + WS_ATTN);
    wo_kernel<<<256, 256, 0, stream>>>(ws + WS_ATTN, Wo, out);
}

// Round 2
// 411.888 us; speedup vs baseline: 1.3372x; 1.3372x over previous
//
#include <hip/hip_runtime.h>
#include <math.h>

#define H 32
#define KV 8
#define D 128
#define PAGE 16
#define TOPK 256
#define NPAGES 2048
#define PAST 32767
#define HID 4096

// workspace layout (float offsets)
#define WS_Q      0        // 4096
#define WS_K      4096     // 1024 (new k, rope'd)
#define WS_V      5120     // 1024 (new v)
#define WS_SCORES 6144     // 32*2048
#define WS_PIDX   71680    // 32*256 ints
#define WS_PART_M 79872    // 32*32
#define WS_PART_L 80896    // 32*32
#define WS_PART_O 81920    // 32*32*128
#define WS_ATTN   212992   // 4096

#define NCHUNK 32          // chunks per head in attention
#define PPC    8           // pages per chunk (TOPK/NCHUNK)

// ---------- 1. QKV projections: q = x@Wq, k = x@Wk, v = x@Wv ----------
__global__ void qkv_kernel(const float* __restrict__ x,
                           const float* __restrict__ Wq,
                           const float* __restrict__ Wk,
                           const float* __restrict__ Wv,
                           float* __restrict__ ws) {
    __shared__ float xs[256];
    int tid = threadIdx.x;
    int rc = blockIdx.x / 24;
    int cg = blockIdx.x % 24;
    int r0 = rc * 256;
    xs[tid] = x[r0 + tid];
    __syncthreads();
    const float* W; int Cc; int col; float* dst;
    if (cg < 16)      { W = Wq; Cc = 4096; col = cg * 256 + tid;        dst = ws + WS_Q + col; }
    else if (cg < 20) { W = Wk; Cc = 1024; col = (cg - 16) * 256 + tid; dst = ws + WS_K + col; }
    else              { W = Wv; Cc = 1024; col = (cg - 20) * 256 + tid; dst = ws + WS_V + col; }
    const float* Wp = W + (size_t)r0 * Cc + col;
    float acc = 0.f;
#pragma unroll 8
    for (int r = 0; r < 256; ++r)
        acc = fmaf(xs[r], Wp[(size_t)r * Cc], acc);
    atomicAdd(dst, acc);
}

// ---------- 2. RoPE on q (32 heads) and k (8 heads), pos = 32767 ----------
__global__ void rope_kernel(float* __restrict__ ws) {
    int idx = blockIdx.x * blockDim.x + threadIdx.x; // 0..2559
    if (idx >= 2560) return;
    float* base;
    if (idx < 2048) base = ws + WS_Q + (idx >> 6) * 128;
    else            base = ws + WS_K + ((idx - 2048) >> 6) * 128;
    int j = idx & 63;
    double t = (double)j / 64.0;
    float p = (float)pow(10000.0, t);   // CR powf
    float invf = 1.0f / p;              // fp32 divide like reference
    float ang = 32767.0f * invf;        // fp32 mul like reference
    float c = (float)cos((double)ang);  // CR cosf on the same fp32 angle
    float s = (float)sin((double)ang);
    float x0 = base[j], x1 = base[j + 64];
    base[j]      = x0 * c - x1 * s;
    base[j + 64] = x1 * c + x0 * s;
}

// ---------- 3. Page scores ----------
__global__ void score_kernel(const float* __restrict__ kc,
                             const float* __restrict__ q,
                             float* __restrict__ scores) {
    int tid = threadIdx.x;
    int lane = tid & 63;
    int wv = tid >> 6;
    int p = blockIdx.x >> 1;
    int kv = ((blockIdx.x & 1) << 2) + wv;
    const float* kp = kc + ((size_t)(p * PAGE) * KV + kv) * D + 2 * lane;
    float mx0 = -INFINITY, mx1 = -INFINITY, mn0 = INFINITY, mn1 = INFINITY;
#pragma unroll
    for (int t = 0; t < PAGE; ++t) {
        float2 v = *(const float2*)(kp + (size_t)t * (KV * D));
        mx0 = fmaxf(mx0, v.x); mn0 = fminf(mn0, v.x);
        mx1 = fmaxf(mx1, v.y); mn1 = fminf(mn1, v.y);
    }
    float sacc[4];
#pragma unroll
    for (int g = 0; g < 4; ++g) {
        int h = kv * 4 + g;
        float q0 = q[h * 128 + 2 * lane];
        float q1 = q[h * 128 + 2 * lane + 1];
        sacc[g] = fmaxf(q0 * mx0, q0 * mn0) + fmaxf(q1 * mx1, q1 * mn1);
    }
#pragma unroll
    for (int off = 32; off > 0; off >>= 1) {
#pragma unroll
        for (int g = 0; g < 4; ++g) sacc[g] += __shfl_xor(sacc[g], off);
    }
    if (lane == 0) {
#pragma unroll
        for (int g = 0; g < 4; ++g)
            scores[(size_t)(kv * 4 + g) * NPAGES + p] = sacc[g];
    }
}

// ---------- 4. Exact top-256 pages per head: radix-256 select, 4 passes ----------
// All-parallel: histogram per 8-bit digit, wave-shuffle suffix scan of 256 bins,
// then ordered parallel compaction for ties (lowest index first, jax tie order).
__global__ void topk_kernel(const float* __restrict__ scores, int* __restrict__ pidx) {
    __shared__ unsigned su[NPAGES];
    __shared__ int hist[256];
    __shared__ int scan[256];
    __shared__ int wtot[4];
    __shared__ int cnt;
    __shared__ unsigned s_prefix;
    __shared__ int s_k;
    int tid = threadIdx.x;
    int lane = tid & 63;
    int wv = tid >> 6;
    int h = blockIdx.x;
    for (int i = tid; i < NPAGES; i += 256) {
        unsigned u;
        if (i == NPAGES - 1) u = 0xFFFFFFFFu;   // last page forced (score=inf in ref)
        else {
            int b = __float_as_int(scores[(size_t)h * NPAGES + i]);
            u = (b >= 0) ? ((unsigned)b | 0x80000000u) : ~(unsigned)b;
        }
        su[i] = u;
    }
    if (tid == 0) cnt = 0;
    __syncthreads();

    unsigned prefix = 0;
    int K = TOPK;
    for (int level = 3; level >= 0; --level) {
        int shift = level * 8;
        unsigned pmask = (level == 3) ? 0u : (0xFFFFFFFFu << (shift + 8));
        hist[tid] = 0;
        __syncthreads();
        for (int i = tid; i < NPAGES; i += 256) {
            unsigned u = su[i];
            if ((u & pmask) == prefix)
                atomicAdd(&hist[(u >> shift) & 0xFF], 1);
        }
        __syncthreads();
        // inclusive suffix scan of hist over 256 bins (wave shuffles + 4 wave totals)
        int v = hist[tid];
#pragma unroll
        for (int off = 1; off < 64; off <<= 1) {
            int o = __shfl_down(v, off);
            if (lane + off < 64) v += o;
        }
        if (lane == 0) wtot[wv] = v;   // wave-inclusive suffix at lane0 = wave sum
        __syncthreads();
        int add = 0;
        for (int w2 = wv + 1; w2 < 4; ++w2) add += wtot[w2];
        v += add;                       // scan[tid] = count(matching elems with digit >= tid)
        scan[tid] = v;
        __syncthreads();
        int nxt = (tid < 255) ? scan[tid + 1] : 0;
        if (v >= K && nxt < K) {
            s_prefix = prefix | ((unsigned)tid << shift);
            s_k = K - nxt;              // ties still needed at/below this digit
        }
        __syncthreads();
        prefix = s_prefix;
        K = s_k;
        __syncthreads();
    }
    unsigned T = prefix;  // the 256th-largest value; K = #ties of T to take

    // strictly-greater elements: unordered positions [0, TOPK-K)
    for (int i = tid; i < NPAGES; i += 256) {
        if (su[i] > T) {
            int pos = atomicAdd(&cnt, 1);
            pidx[h * TOPK + pos] = i;
        }
    }
    // ties == T: ordered by index (lowest first), positions [TOPK-K, TOPK)
    int base = TOPK - K;
    int i0 = tid * (NPAGES / 256);
    int tcount = 0;
#pragma unroll
    for (int j = 0; j < NPAGES / 256; ++j) if (su[i0 + j] == T) ++tcount;
    int sc = tcount;
#pragma unroll
    for (int off = 1; off < 64; off <<= 1) {
        int o = __shfl_up(sc, off);
        if (lane >= off) sc += o;
    }
    __syncthreads();               // wtot reuse: prior reads are behind barriers
    if (lane == 63) wtot[wv] = sc; // wave total
    __syncthreads();
    int wadd = 0;
    for (int w2 = 0; w2 < wv; ++w2) wadd += wtot[w2];
    int pos = base + (sc - tcount) + wadd;   // global exclusive tie-rank
#pragma unroll
    for (int j = 0; j < NPAGES / 256; ++j) {
        if (su[i0 + j] == T) {
            if (pos < TOPK) pidx[h * TOPK + pos] = i0 + j;
            ++pos;
        }
    }
}

// ---------- 5. Sparse attention, chunked online softmax ----------
__global__ void attn_kernel(const float* __restrict__ kc,
                            const float* __restrict__ vc,
                            const float* __restrict__ ws,
                            const int* __restrict__ pidx,
                            float* __restrict__ part_m,
                            float* __restrict__ part_l,
                            float* __restrict__ part_o) {
    int tid = threadIdx.x;
    int lane = tid & 63;
    int wv = tid >> 6;
    int h = blockIdx.x >> 5;
    int c = blockIdx.x & 31;
    int kvh = h >> 2;
    __shared__ float qs[128];
    __shared__ float sm[4], sl[4];
    __shared__ float so[4 * 128];
    if (tid < 128) qs[tid] = ws[WS_Q + h * 128 + tid];
    __syncthreads();
    float q0 = qs[2 * lane], q1 = qs[2 * lane + 1];
    float m = -INFINITY, l = 0.f, o0 = 0.f, o1 = 0.f;
    const float scale = 0.08838834764831843f; // fp32(1/sqrt(128))
    for (int pi = 0; pi < 2; ++pi) {
        int page = pidx[h * TOPK + c * PPC + wv * 2 + pi];
        for (int t = 0; t < PAGE; ++t) {
            int tok = page * PAGE + t;
            const float *kp, *vp;
            if (tok == PAST) { kp = ws + WS_K + kvh * 128; vp = ws + WS_V + kvh * 128; }
            else {
                size_t off = ((size_t)tok * KV + kvh) * D;
                kp = kc + off; vp = vc + off;
            }
            float2 kk = *(const float2*)(kp + 2 * lane);
            float s = q0 * kk.x + q1 * kk.y;
#pragma unroll
            for (int off2 = 32; off2 > 0; off2 >>= 1) s += __shfl_xor(s, off2);
            s *= scale;
            float2 vvv = *(const float2*)(vp + 2 * lane);
            float nm = fmaxf(m, s);
            float rs = expf(m - nm);
            float w = expf(s - nm);
            l = l * rs + w;
            o0 = o0 * rs + w * vvv.x;
            o1 = o1 * rs + w * vvv.y;
            m = nm;
        }
    }
    if (lane == 0) { sm[wv] = m; sl[wv] = l; }
    so[wv * 128 + 2 * lane]     = o0;
    so[wv * 128 + 2 * lane + 1] = o1;
    __syncthreads();
    if (tid < 128) {
        float M = fmaxf(fmaxf(sm[0], sm[1]), fmaxf(sm[2], sm[3]));
        float L = 0.f, O = 0.f;
#pragma unroll
        for (int w2 = 0; w2 < 4; ++w2) {
            float f = expf(sm[w2] - M);
            L += f * sl[w2];
            O += f * so[w2 * 128 + tid];
        }
        int pc = h * NCHUNK + c;
        if (tid == 0) { part_m[pc] = M; part_l[pc] = L; }
        part_o[(size_t)pc * 128 + tid] = O;
    }
}

// ---------- 6. Combine chunk partials -> attn_out (32 x 128) ----------
__global__ void combine_kernel(const float* __restrict__ part_m,
                               const float* __restrict__ part_l,
                               const float* __restrict__ part_o,
                               float* __restrict__ attn) {
    int h = blockIdx.x;
    int d = threadIdx.x; // 128
    float M = -INFINITY;
    for (int c = 0; c < NCHUNK; ++c) M = fmaxf(M, part_m[h * NCHUNK + c]);
    float L = 0.f, O = 0.f;
    for (int c = 0; c < NCHUNK; ++c) {
        float f = expf(part_m[h * NCHUNK + c] - M);
        L += f * part_l[h * NCHUNK + c];
        O += f * part_o[(size_t)(h * NCHUNK + c) * 128 + d];
    }
    attn[h * 128 + d] = O / L;
}

// ---------- 7. Output projection: y = attn @ Wo ----------
__global__ void wo_kernel(const float* __restrict__ attn,
                          const float* __restrict__ Wo,
                          float* __restrict__ out) {
    __shared__ float xs[256];
    int tid = threadIdx.x;
    int rc = blockIdx.x >> 4;
    int cb = blockIdx.x & 15;
    int r0 = rc * 256;
    xs[tid] = attn[r0 + tid];
    __syncthreads();
    int col = cb * 256 + tid;
    const float* Wp = Wo + (size_t)r0 * 4096 + col;
    float acc = 0.f;
#pragma unroll 8
    for (int r = 0; r < 256; ++r)
        acc = fmaf(xs[r], Wp[(size_t)r * 4096], acc);
    atomicAdd(out + col, acc);
}

extern "C" void kernel_launch(void* const* d_in, const int* in_sizes, int n_in,
                              void* d_out, int out_size, void* d_ws, size_t ws_size,
                              hipStream_t stream) {
    const float* x  = (const float*)d_in[0];
    const float* kc = (const float*)d_in[1];
    const float* vc = (const float*)d_in[2];
    const float* Wq = (const float*)d_in[3];
    const float* Wk = (const float*)d_in[4];
    const float* Wv = (const float*)d_in[5];
    const float* Wo = (const float*)d_in[6];
    float* ws = (float*)d_ws;
    float* out = (float*)d_out;

    hipMemsetAsync(ws, 0, 6144 * sizeof(float), stream);
    hipMemsetAsync(out, 0, (size_t)out_size * sizeof(float), stream);

    qkv_kernel<<<384, 256, 0, stream>>>(x, Wq, Wk, Wv, ws);
    rope_kernel<<<10, 256, 0, stream>>>(ws);
    score_kernel<<<(NPAGES - 1) * 2, 256, 0, stream>>>(kc, ws + WS_Q, ws + WS_SCORES);
    topk_kernel<<<H, 256, 0, stream>>>(ws + WS_SCORES, (int*)(ws + WS_PIDX));
    attn_kernel<<<H * NCHUNK, 256, 0, stream>>>(kc, vc, ws, (const int*)(ws + WS_PIDX),
                                                ws + WS_PART_M, ws + WS_PART_L, ws + WS_PART_O);
    combine_kernel<<<H, 128, 0, stream>>>(ws + WS_PART_M, ws + WS_PART_L, ws + WS_PART_O,
                                          ws + WS_ATTN);
    wo_kernel<<<256, 256, 0, stream>>>(ws + WS_ATTN, Wo, out);
}

// Round 3
// 402.705 us; speedup vs baseline: 1.3677x; 1.0228x over previous
//
#include <hip/hip_runtime.h>
#include <math.h>

#define H 32
#define KV 8
#define D 128
#define PAGE 16
#define TOPK 256
#define NPAGES 2048
#define PAST 32767
#define HID 4096

// workspace layout (float offsets)
#define WS_Q      0        // 4096
#define WS_K      4096     // 1024 (new k, rope'd)
#define WS_V      5120     // 1024 (new v)
#define WS_SCORES 6144     // 32*2048
#define WS_PIDX   71680    // 32*256 ints
#define WS_PART_M 79872    // 32*32
#define WS_PART_L 80896    // 32*32
#define WS_PART_O 81920    // 32*32*128
#define WS_ATTN   212992   // 4096

#define NCHUNK 32          // chunks per head in attention
#define PPC    8           // pages per chunk (TOPK/NCHUNK)

// ---------- 1. QKV projections: float4 loads, 64-row x 1024-col blocks ----------
__global__ void qkv_kernel(const float* __restrict__ x,
                           const float* __restrict__ Wq,
                           const float* __restrict__ Wk,
                           const float* __restrict__ Wv,
                           float* __restrict__ ws) {
    __shared__ float xs[64];
    int tid = threadIdx.x;
    int rc = blockIdx.x / 6;
    int cg = blockIdx.x % 6;
    int r0 = rc * 64;
    if (tid < 64) xs[tid] = x[r0 + tid];
    __syncthreads();
    const float* W; int Cc; int col; float* dst;
    if (cg < 4)       { W = Wq; Cc = 4096; col = cg * 1024 + tid * 4; dst = ws + WS_Q + col; }
    else if (cg == 4) { W = Wk; Cc = 1024; col = tid * 4;             dst = ws + WS_K + col; }
    else              { W = Wv; Cc = 1024; col = tid * 4;             dst = ws + WS_V + col; }
    const float* Wp = W + (size_t)r0 * Cc + col;
    float4 acc = {0.f, 0.f, 0.f, 0.f};
#pragma unroll 8
    for (int r = 0; r < 64; ++r) {
        float4 w4 = *(const float4*)(Wp + (size_t)r * Cc);
        float xr = xs[r];
        acc.x = fmaf(xr, w4.x, acc.x);
        acc.y = fmaf(xr, w4.y, acc.y);
        acc.z = fmaf(xr, w4.z, acc.z);
        acc.w = fmaf(xr, w4.w, acc.w);
    }
    atomicAdd(dst + 0, acc.x);
    atomicAdd(dst + 1, acc.y);
    atomicAdd(dst + 2, acc.z);
    atomicAdd(dst + 3, acc.w);
}

// ---------- 2. RoPE on q (32 heads) and k (8 heads), pos = 32767 ----------
__global__ void rope_kernel(float* __restrict__ ws) {
    int idx = blockIdx.x * blockDim.x + threadIdx.x; // 0..2559
    if (idx >= 2560) return;
    float* base;
    if (idx < 2048) base = ws + WS_Q + (idx >> 6) * 128;
    else            base = ws + WS_K + ((idx - 2048) >> 6) * 128;
    int j = idx & 63;
    double t = (double)j / 64.0;
    float p = (float)pow(10000.0, t);   // CR powf
    float invf = 1.0f / p;              // fp32 divide like reference
    float ang = 32767.0f * invf;        // fp32 mul like reference
    float c = (float)cos((double)ang);  // CR cosf on the same fp32 angle
    float s = (float)sin((double)ang);
    float x0 = base[j], x1 = base[j + 64];
    base[j]      = x0 * c - x1 * s;
    base[j + 64] = x1 * c + x0 * s;
}

// ---------- 3. Page scores: float4, half-wave per token parity ----------
__global__ void score_kernel(const float* __restrict__ kc,
                             const float* __restrict__ q,
                             float* __restrict__ scores) {
    int tid = threadIdx.x;
    int lane = tid & 63;
    int wv = tid >> 6;
    int sub = lane & 31;
    int hf = lane >> 5;
    int p = blockIdx.x >> 1;
    int kv = ((blockIdx.x & 1) << 2) + wv;
    const float* kp0 = kc + ((size_t)(p * PAGE) * KV + kv) * D + 4 * sub;
    float4 mx = {-INFINITY, -INFINITY, -INFINITY, -INFINITY};
    float4 mn = { INFINITY,  INFINITY,  INFINITY,  INFINITY};
#pragma unroll
    for (int s8 = 0; s8 < 8; ++s8) {
        int t = 2 * s8 + hf;
        float4 v = *(const float4*)(kp0 + (size_t)t * (KV * D));
        mx.x = fmaxf(mx.x, v.x); mn.x = fminf(mn.x, v.x);
        mx.y = fmaxf(mx.y, v.y); mn.y = fminf(mn.y, v.y);
        mx.z = fmaxf(mx.z, v.z); mn.z = fminf(mn.z, v.z);
        mx.w = fmaxf(mx.w, v.w); mn.w = fminf(mn.w, v.w);
    }
    // merge the two halves (lanes l and l+32 hold the same dims)
    mx.x = fmaxf(mx.x, __shfl_xor(mx.x, 32)); mn.x = fminf(mn.x, __shfl_xor(mn.x, 32));
    mx.y = fmaxf(mx.y, __shfl_xor(mx.y, 32)); mn.y = fminf(mn.y, __shfl_xor(mn.y, 32));
    mx.z = fmaxf(mx.z, __shfl_xor(mx.z, 32)); mn.z = fminf(mn.z, __shfl_xor(mn.z, 32));
    mx.w = fmaxf(mx.w, __shfl_xor(mx.w, 32)); mn.w = fminf(mn.w, __shfl_xor(mn.w, 32));
    float sacc[4];
#pragma unroll
    for (int g = 0; g < 4; ++g) {
        float4 qq = *(const float4*)(q + (size_t)(kv * 4 + g) * 128 + 4 * sub);
        sacc[g] = fmaxf(qq.x * mx.x, qq.x * mn.x) + fmaxf(qq.y * mx.y, qq.y * mn.y)
                + fmaxf(qq.z * mx.z, qq.z * mn.z) + fmaxf(qq.w * mx.w, qq.w * mn.w);
    }
#pragma unroll
    for (int off = 16; off > 0; off >>= 1) {
#pragma unroll
        for (int g = 0; g < 4; ++g) sacc[g] += __shfl_xor(sacc[g], off);
    }
    if (lane == 0) {
#pragma unroll
        for (int g = 0; g < 4; ++g)
            scores[(size_t)(kv * 4 + g) * NPAGES + p] = sacc[g];
    }
}

// ---------- 4. Exact top-256 pages per head: radix-256 select, 4 passes ----------
__global__ void topk_kernel(const float* __restrict__ scores, int* __restrict__ pidx) {
    __shared__ unsigned su[NPAGES];
    __shared__ int hist[256];
    __shared__ int scan[256];
    __shared__ int wtot[4];
    __shared__ int cnt;
    __shared__ unsigned s_prefix;
    __shared__ int s_k;
    int tid = threadIdx.x;
    int lane = tid & 63;
    int wv = tid >> 6;
    int h = blockIdx.x;
    for (int i = tid; i < NPAGES; i += 256) {
        unsigned u;
        if (i == NPAGES - 1) u = 0xFFFFFFFFu;   // last page forced (score=inf in ref)
        else {
            int b = __float_as_int(scores[(size_t)h * NPAGES + i]);
            u = (b >= 0) ? ((unsigned)b | 0x80000000u) : ~(unsigned)b;
        }
        su[i] = u;
    }
    if (tid == 0) cnt = 0;
    __syncthreads();

    unsigned prefix = 0;
    int K = TOPK;
    for (int level = 3; level >= 0; --level) {
        int shift = level * 8;
        unsigned pmask = (level == 3) ? 0u : (0xFFFFFFFFu << (shift + 8));
        hist[tid] = 0;
        __syncthreads();
        for (int i = tid; i < NPAGES; i += 256) {
            unsigned u = su[i];
            if ((u & pmask) == prefix)
                atomicAdd(&hist[(u >> shift) & 0xFF], 1);
        }
        __syncthreads();
        int v = hist[tid];
#pragma unroll
        for (int off = 1; off < 64; off <<= 1) {
            int o = __shfl_down(v, off);
            if (lane + off < 64) v += o;
        }
        if (lane == 0) wtot[wv] = v;
        __syncthreads();
        int add = 0;
        for (int w2 = wv + 1; w2 < 4; ++w2) add += wtot[w2];
        v += add;
        scan[tid] = v;
        __syncthreads();
        int nxt = (tid < 255) ? scan[tid + 1] : 0;
        if (v >= K && nxt < K) {
            s_prefix = prefix | ((unsigned)tid << shift);
            s_k = K - nxt;
        }
        __syncthreads();
        prefix = s_prefix;
        K = s_k;
        __syncthreads();
    }
    unsigned T = prefix;

    for (int i = tid; i < NPAGES; i += 256) {
        if (su[i] > T) {
            int pos = atomicAdd(&cnt, 1);
            pidx[h * TOPK + pos] = i;
        }
    }
    int base = TOPK - K;
    int i0 = tid * (NPAGES / 256);
    int tcount = 0;
#pragma unroll
    for (int j = 0; j < NPAGES / 256; ++j) if (su[i0 + j] == T) ++tcount;
    int sc = tcount;
#pragma unroll
    for (int off = 1; off < 64; off <<= 1) {
        int o = __shfl_up(sc, off);
        if (lane >= off) sc += o;
    }
    __syncthreads();
    if (lane == 63) wtot[wv] = sc;
    __syncthreads();
    int wadd = 0;
    for (int w2 = 0; w2 < wv; ++w2) wadd += wtot[w2];
    int pos = base + (sc - tcount) + wadd;
#pragma unroll
    for (int j = 0; j < NPAGES / 256; ++j) {
        if (su[i0 + j] == T) {
            if (pos < TOPK) pidx[h * TOPK + pos] = i0 + j;
            ++pos;
        }
    }
}

// ---------- 5. Sparse attention: half-wave per page, two-phase softmax, float4 ----------
__global__ void attn_kernel(const float* __restrict__ kc,
                            const float* __restrict__ vc,
                            const float* __restrict__ ws,
                            const int* __restrict__ pidx,
                            float* __restrict__ part_m,
                            float* __restrict__ part_l,
                            float* __restrict__ part_o) {
    int tid = threadIdx.x;
    int lane = tid & 63;
    int wv = tid >> 6;
    int sub = lane & 31;
    int hf = lane >> 5;
    int h = blockIdx.x >> 5;
    int c = blockIdx.x & 31;
    int kvh = h >> 2;
    __shared__ float qs[128];
    __shared__ float sm[8], sl[8];
    __shared__ float so[8 * 128];
    if (tid < 128) qs[tid] = ws[WS_Q + h * 128 + tid];
    __syncthreads();
    float4 q4 = *(const float4*)(qs + 4 * sub);
    int hidx = wv * 2 + hf;
    int page = pidx[h * TOPK + c * PPC + hidx];
    size_t base = ((size_t)(page * PAGE) * KV + kvh) * D + 4 * sub;
    bool last = (page == NPAGES - 1);
    const float scale = 0.08838834764831843f; // fp32(1/sqrt(128))

    float s[PAGE];
#pragma unroll
    for (int t = 0; t < PAGE; ++t) {
        const float* kp = (last && t == PAGE - 1) ? (ws + WS_K + kvh * 128 + 4 * sub)
                                                  : (kc + base + (size_t)t * (KV * D));
        float4 kk = *(const float4*)kp;
        float d = q4.x * kk.x + q4.y * kk.y + q4.z * kk.z + q4.w * kk.w;
#pragma unroll
        for (int off = 16; off > 0; off >>= 1) d += __shfl_xor(d, off);
        s[t] = d * scale;
    }
    float m = -INFINITY;
#pragma unroll
    for (int t = 0; t < PAGE; ++t) m = fmaxf(m, s[t]);
    float l = 0.f;
    float4 o = {0.f, 0.f, 0.f, 0.f};
#pragma unroll
    for (int t = 0; t < PAGE; ++t) {
        float w = expf(s[t] - m);
        l += w;
        const float* vp = (last && t == PAGE - 1) ? (ws + WS_V + kvh * 128 + 4 * sub)
                                                  : (vc + base + (size_t)t * (KV * D));
        float4 vv = *(const float4*)vp;
        o.x = fmaf(w, vv.x, o.x);
        o.y = fmaf(w, vv.y, o.y);
        o.z = fmaf(w, vv.z, o.z);
        o.w = fmaf(w, vv.w, o.w);
    }
    if (sub == 0) { sm[hidx] = m; sl[hidx] = l; }
    *(float4*)(so + hidx * 128 + 4 * sub) = o;
    __syncthreads();
    if (tid < 128) {
        float M = -INFINITY;
#pragma unroll
        for (int w2 = 0; w2 < 8; ++w2) M = fmaxf(M, sm[w2]);
        float L = 0.f, O = 0.f;
#pragma unroll
        for (int w2 = 0; w2 < 8; ++w2) {
            float f = expf(sm[w2] - M);
            L += f * sl[w2];
            O += f * so[w2 * 128 + tid];
        }
        int pc = h * NCHUNK + c;
        if (tid == 0) { part_m[pc] = M; part_l[pc] = L; }
        part_o[(size_t)pc * 128 + tid] = O;
    }
}

// ---------- 6. Combine chunk partials -> attn_out (32 x 128) ----------
__global__ void combine_kernel(const float* __restrict__ part_m,
                               const float* __restrict__ part_l,
                               const float* __restrict__ part_o,
                               float* __restrict__ attn) {
    int h = blockIdx.x;
    int d = threadIdx.x; // 128
    float M = -INFINITY;
    for (int c = 0; c < NCHUNK; ++c) M = fmaxf(M, part_m[h * NCHUNK + c]);
    float L = 0.f, O = 0.f;
    for (int c = 0; c < NCHUNK; ++c) {
        float f = expf(part_m[h * NCHUNK + c] - M);
        L += f * part_l[h * NCHUNK + c];
        O += f * part_o[(size_t)(h * NCHUNK + c) * 128 + d];
    }
    attn[h * 128 + d] = O / L;
}

// ---------- 7. Output projection: float4, 64-row x 1024-col blocks ----------
__global__ void wo_kernel(const float* __restrict__ attn,
                          const float* __restrict__ Wo,
                          float* __restrict__ out) {
    __shared__ float xs[64];
    int tid = threadIdx.x;
    int rc = blockIdx.x >> 2;
    int cb = blockIdx.x & 3;
    int r0 = rc * 64;
    if (tid < 64) xs[tid] = attn[r0 + tid];
    __syncthreads();
    int col = cb * 1024 + tid * 4;
    const float* Wp = Wo + (size_t)r0 * 4096 + col;
    float4 acc = {0.f, 0.f, 0.f, 0.f};
#pragma unroll 8
    for (int r = 0; r < 64; ++r) {
        float4 w4 = *(const float4*)(Wp + (size_t)r * 4096);
        float xr = xs[r];
        acc.x = fmaf(xr, w4.x, acc.x);
        acc.y = fmaf(xr, w4.y, acc.y);
        acc.z = fmaf(xr, w4.z, acc.z);
        acc.w = fmaf(xr, w4.w, acc.w);
    }
    atomicAdd(out + col + 0, acc.x);
    atomicAdd(out + col + 1, acc.y);
    atomicAdd(out + col + 2, acc.z);
    atomicAdd(out + col + 3, acc.w);
}

extern "C" void kernel_launch(void* const* d_in, const int* in_sizes, int n_in,
                              void* d_out, int out_size, void* d_ws, size_t ws_size,
                              hipStream_t stream) {
    const float* x  = (const float*)d_in[0];
    const float* kc = (const float*)d_in[1];
    const float* vc = (const float*)d_in[2];
    const float* Wq = (const float*)d_in[3];
    const float* Wk = (const float*)d_in[4];
    const float* Wv = (const float*)d_in[5];
    const float* Wo = (const float*)d_in[6];
    float* ws = (float*)d_ws;
    float* out = (float*)d_out;

    hipMemsetAsync(ws, 0, 6144 * sizeof(float), stream);
    hipMemsetAsync(out, 0, (size_t)out_size * sizeof(float), stream);

    qkv_kernel<<<384, 256, 0, stream>>>(x, Wq, Wk, Wv, ws);
    rope_kernel<<<10, 256, 0, stream>>>(ws);
    score_kernel<<<(NPAGES - 1) * 2, 256, 0, stream>>>(kc, ws + WS_Q, ws + WS_SCORES);
    topk_kernel<<<H, 256, 0, stream>>>(ws + WS_SCORES, (int*)(ws + WS_PIDX));
    attn_kernel<<<H * NCHUNK, 256, 0, stream>>>(kc, vc, ws, (const int*)(ws + WS_PIDX),
                                                ws + WS_PART_M, ws + WS_PART_L, ws + WS_PART_O);
    combine_kernel<<<H, 128, 0, stream>>>(ws + WS_PART_M, ws + WS_PART_L, ws + WS_PART_O,
                                          ws + WS_ATTN);
    wo_kernel<<<256, 256, 0, stream>>>(ws + WS_ATTN, Wo, out);
}

// Round 4
// 400.702 us; speedup vs baseline: 1.3745x; 1.0050x over previous
//
#include <hip/hip_runtime.h>
#include <math.h>

#define H 32
#define KV 8
#define D 128
#define PAGE 16
#define TOPK 256
#define NPAGES 2048
#define PAST 32767
#define HID 4096

// workspace layout (float offsets)
#define WS_Q       0        // 4096 (q | k | v contiguous: 6144 total)
#define WS_K       4096     // 1024
#define WS_V       5120     // 1024
#define WS_SCORES  6144     // 32*2048
#define WS_PIDX    71680    // 32*256 ints
#define WS_PART_M  79872    // 32*32
#define WS_PART_L  80896    // 32*32
#define WS_PART_O  81920    // 32*32*128
#define WS_QKVPART 212992   // 64*6144
#define WS_WOPART  606208   // 64*4096

#define NCHUNK 32           // chunks per head in attention
#define PPC    8            // pages per chunk (TOPK/NCHUNK)

// ---------- 1a. QKV partials: 64-row x 1024-col blocks, disjoint stores ----------
__global__ void qkv1_kernel(const float* __restrict__ x,
                            const float* __restrict__ Wq,
                            const float* __restrict__ Wk,
                            const float* __restrict__ Wv,
                            float* __restrict__ part) {
    __shared__ float xs[64];
    int tid = threadIdx.x;
    int rc = blockIdx.x / 6;
    int cg = blockIdx.x % 6;
    int r0 = rc * 64;
    if (tid < 64) xs[tid] = x[r0 + tid];
    __syncthreads();
    const float* W; int Cc; int col; int gcol;
    if (cg < 4)       { W = Wq; Cc = 4096; col = cg * 1024 + tid * 4; gcol = col; }
    else if (cg == 4) { W = Wk; Cc = 1024; col = tid * 4;             gcol = 4096 + col; }
    else              { W = Wv; Cc = 1024; col = tid * 4;             gcol = 5120 + col; }
    const float* Wp = W + (size_t)r0 * Cc + col;
    float4 acc = {0.f, 0.f, 0.f, 0.f};
#pragma unroll 8
    for (int r = 0; r < 64; ++r) {
        float4 w4 = *(const float4*)(Wp + (size_t)r * Cc);
        float xr = xs[r];
        acc.x = fmaf(xr, w4.x, acc.x);
        acc.y = fmaf(xr, w4.y, acc.y);
        acc.z = fmaf(xr, w4.z, acc.z);
        acc.w = fmaf(xr, w4.w, acc.w);
    }
    *(float4*)(part + (size_t)rc * 6144 + gcol) = acc;
}

// ---------- 1b. Reduce 64 partials/col + fused RoPE (pos=32767) ----------
// 24 blocks x 256 thr; block covers 256 consecutive cols (head-half pairs stay in-block).
__global__ void reduce_rope_kernel(const float* __restrict__ part,
                                   float* __restrict__ qkv) {
    __shared__ float smem[256];
    int tid = threadIdx.x;
    int c = blockIdx.x * 256 + tid;   // global col 0..6143
    float s = 0.f;
#pragma unroll 8
    for (int rc = 0; rc < 64; ++rc) s += part[(size_t)rc * 6144 + c];
    smem[tid] = s;
    __syncthreads();
    float outv;
    if (c < 5120) {  // q (0..4095) and k (4096..5119): rope
        int j = c & 127;
        int jj = (j < 64) ? j : (j - 64);
        double t = (double)jj / 64.0;
        float p = (float)pow(10000.0, t);   // CR powf
        float invf = 1.0f / p;
        float ang = 32767.0f * invf;
        float co = (float)cos((double)ang); // CR cosf on same fp32 angle
        float si = (float)sin((double)ang);
        if (j < 64) { float x0 = s, x1 = smem[tid + 64]; outv = x0 * co - x1 * si; }
        else        { float x1 = s, x0 = smem[tid - 64]; outv = x1 * co + x0 * si; }
    } else {
        outv = s;   // v passthrough
    }
    qkv[c] = outv;
}

// ---------- 2. Page scores: float4, half-wave per token parity ----------
__global__ void score_kernel(const float* __restrict__ kc,
                             const float* __restrict__ q,
                             float* __restrict__ scores) {
    int tid = threadIdx.x;
    int lane = tid & 63;
    int wv = tid >> 6;
    int sub = lane & 31;
    int hf = lane >> 5;
    int p = blockIdx.x >> 1;
    int kv = ((blockIdx.x & 1) << 2) + wv;
    const float* kp0 = kc + ((size_t)(p * PAGE) * KV + kv) * D + 4 * sub;
    float4 mx = {-INFINITY, -INFINITY, -INFINITY, -INFINITY};
    float4 mn = { INFINITY,  INFINITY,  INFINITY,  INFINITY};
#pragma unroll
    for (int s8 = 0; s8 < 8; ++s8) {
        int t = 2 * s8 + hf;
        float4 v = *(const float4*)(kp0 + (size_t)t * (KV * D));
        mx.x = fmaxf(mx.x, v.x); mn.x = fminf(mn.x, v.x);
        mx.y = fmaxf(mx.y, v.y); mn.y = fminf(mn.y, v.y);
        mx.z = fmaxf(mx.z, v.z); mn.z = fminf(mn.z, v.z);
        mx.w = fmaxf(mx.w, v.w); mn.w = fminf(mn.w, v.w);
    }
    mx.x = fmaxf(mx.x, __shfl_xor(mx.x, 32)); mn.x = fminf(mn.x, __shfl_xor(mn.x, 32));
    mx.y = fmaxf(mx.y, __shfl_xor(mx.y, 32)); mn.y = fminf(mn.y, __shfl_xor(mn.y, 32));
    mx.z = fmaxf(mx.z, __shfl_xor(mx.z, 32)); mn.z = fminf(mn.z, __shfl_xor(mn.z, 32));
    mx.w = fmaxf(mx.w, __shfl_xor(mx.w, 32)); mn.w = fminf(mn.w, __shfl_xor(mn.w, 32));
    float sacc[4];
#pragma unroll
    for (int g = 0; g < 4; ++g) {
        float4 qq = *(const float4*)(q + (size_t)(kv * 4 + g) * 128 + 4 * sub);
        sacc[g] = fmaxf(qq.x * mx.x, qq.x * mn.x) + fmaxf(qq.y * mx.y, qq.y * mn.y)
                + fmaxf(qq.z * mx.z, qq.z * mn.z) + fmaxf(qq.w * mx.w, qq.w * mn.w);
    }
#pragma unroll
    for (int off = 16; off > 0; off >>= 1) {
#pragma unroll
        for (int g = 0; g < 4; ++g) sacc[g] += __shfl_xor(sacc[g], off);
    }
    if (lane == 0) {
#pragma unroll
        for (int g = 0; g < 4; ++g)
            scores[(size_t)(kv * 4 + g) * NPAGES + p] = sacc[g];
    }
}

// ---------- 3. Exact top-256 pages per head: radix-256 select, 4 passes ----------
__global__ void topk_kernel(const float* __restrict__ scores, int* __restrict__ pidx) {
    __shared__ unsigned su[NPAGES];
    __shared__ int hist[256];
    __shared__ int scan[256];
    __shared__ int wtot[4];
    __shared__ int cnt;
    __shared__ unsigned s_prefix;
    __shared__ int s_k;
    int tid = threadIdx.x;
    int lane = tid & 63;
    int wv = tid >> 6;
    int h = blockIdx.x;
    for (int i = tid; i < NPAGES; i += 256) {
        unsigned u;
        if (i == NPAGES - 1) u = 0xFFFFFFFFu;   // last page forced (score=inf in ref)
        else {
            int b = __float_as_int(scores[(size_t)h * NPAGES + i]);
            u = (b >= 0) ? ((unsigned)b | 0x80000000u) : ~(unsigned)b;
        }
        su[i] = u;
    }
    if (tid == 0) cnt = 0;
    __syncthreads();

    unsigned prefix = 0;
    int K = TOPK;
    for (int level = 3; level >= 0; --level) {
        int shift = level * 8;
        unsigned pmask = (level == 3) ? 0u : (0xFFFFFFFFu << (shift + 8));
        hist[tid] = 0;
        __syncthreads();
        for (int i = tid; i < NPAGES; i += 256) {
            unsigned u = su[i];
            if ((u & pmask) == prefix)
                atomicAdd(&hist[(u >> shift) & 0xFF], 1);
        }
        __syncthreads();
        int v = hist[tid];
#pragma unroll
        for (int off = 1; off < 64; off <<= 1) {
            int o = __shfl_down(v, off);
            if (lane + off < 64) v += o;
        }
        if (lane == 0) wtot[wv] = v;
        __syncthreads();
        int add = 0;
        for (int w2 = wv + 1; w2 < 4; ++w2) add += wtot[w2];
        v += add;
        scan[tid] = v;
        __syncthreads();
        int nxt = (tid < 255) ? scan[tid + 1] : 0;
        if (v >= K && nxt < K) {
            s_prefix = prefix | ((unsigned)tid << shift);
            s_k = K - nxt;
        }
        __syncthreads();
        prefix = s_prefix;
        K = s_k;
        __syncthreads();
    }
    unsigned T = prefix;

    for (int i = tid; i < NPAGES; i += 256) {
        if (su[i] > T) {
            int pos = atomicAdd(&cnt, 1);
            pidx[h * TOPK + pos] = i;
        }
    }
    int base = TOPK - K;
    int i0 = tid * (NPAGES / 256);
    int tcount = 0;
#pragma unroll
    for (int j = 0; j < NPAGES / 256; ++j) if (su[i0 + j] == T) ++tcount;
    int sc = tcount;
#pragma unroll
    for (int off = 1; off < 64; off <<= 1) {
        int o = __shfl_up(sc, off);
        if (lane >= off) sc += o;
    }
    __syncthreads();
    if (lane == 63) wtot[wv] = sc;
    __syncthreads();
    int wadd = 0;
    for (int w2 = 0; w2 < wv; ++w2) wadd += wtot[w2];
    int pos = base + (sc - tcount) + wadd;
#pragma unroll
    for (int j = 0; j < NPAGES / 256; ++j) {
        if (su[i0 + j] == T) {
            if (pos < TOPK) pidx[h * TOPK + pos] = i0 + j;
            ++pos;
        }
    }
}

// ---------- 4. Sparse attention: half-wave per page, two-phase softmax, float4 ----------
__global__ void attn_kernel(const float* __restrict__ kc,
                            const float* __restrict__ vc,
                            const float* __restrict__ ws,
                            const int* __restrict__ pidx,
                            float* __restrict__ part_m,
                            float* __restrict__ part_l,
                            float* __restrict__ part_o) {
    int tid = threadIdx.x;
    int lane = tid & 63;
    int wv = tid >> 6;
    int sub = lane & 31;
    int hf = lane >> 5;
    int h = blockIdx.x >> 5;
    int c = blockIdx.x & 31;
    int kvh = h >> 2;
    __shared__ float qs[128];
    __shared__ float sm[8], sl[8];
    __shared__ float so[8 * 128];
    if (tid < 128) qs[tid] = ws[WS_Q + h * 128 + tid];
    __syncthreads();
    float4 q4 = *(const float4*)(qs + 4 * sub);
    int hidx = wv * 2 + hf;
    int page = pidx[h * TOPK + c * PPC + hidx];
    size_t base = ((size_t)(page * PAGE) * KV + kvh) * D + 4 * sub;
    bool last = (page == NPAGES - 1);
    const float scale = 0.08838834764831843f; // fp32(1/sqrt(128))

    float s[PAGE];
#pragma unroll
    for (int t = 0; t < PAGE; ++t) {
        const float* kp = (last && t == PAGE - 1) ? (ws + WS_K + kvh * 128 + 4 * sub)
                                                  : (kc + base + (size_t)t * (KV * D));
        float4 kk = *(const float4*)kp;
        float d = q4.x * kk.x + q4.y * kk.y + q4.z * kk.z + q4.w * kk.w;
#pragma unroll
        for (int off = 16; off > 0; off >>= 1) d += __shfl_xor(d, off);
        s[t] = d * scale;
    }
    float m = -INFINITY;
#pragma unroll
    for (int t = 0; t < PAGE; ++t) m = fmaxf(m, s[t]);
    float l = 0.f;
    float4 o = {0.f, 0.f, 0.f, 0.f};
#pragma unroll
    for (int t = 0; t < PAGE; ++t) {
        float w = __expf(s[t] - m);
        l += w;
        const float* vp = (last && t == PAGE - 1) ? (ws + WS_V + kvh * 128 + 4 * sub)
                                                  : (vc + base + (size_t)t * (KV * D));
        float4 vv = *(const float4*)vp;
        o.x = fmaf(w, vv.x, o.x);
        o.y = fmaf(w, vv.y, o.y);
        o.z = fmaf(w, vv.z, o.z);
        o.w = fmaf(w, vv.w, o.w);
    }
    if (sub == 0) { sm[hidx] = m; sl[hidx] = l; }
    *(float4*)(so + hidx * 128 + 4 * sub) = o;
    __syncthreads();
    if (tid < 128) {
        float M = -INFINITY;
#pragma unroll
        for (int w2 = 0; w2 < 8; ++w2) M = fmaxf(M, sm[w2]);
        float L = 0.f, O = 0.f;
#pragma unroll
        for (int w2 = 0; w2 < 8; ++w2) {
            float f = __expf(sm[w2] - M);
            L += f * sl[w2];
            O += f * so[w2 * 128 + tid];
        }
        int pc = h * NCHUNK + c;
        if (tid == 0) { part_m[pc] = M; part_l[pc] = L; }
        part_o[(size_t)pc * 128 + tid] = O;
    }
}

// ---------- 5a. Output projection stage 1: fused combine + 64x1024 partials ----------
__global__ void wo1_kernel(const float* __restrict__ part_m,
                           const float* __restrict__ part_l,
                           const float* __restrict__ part_o,
                           const float* __restrict__ Wo,
                           float* __restrict__ wpart) {
    __shared__ float xs[64];
    int tid = threadIdx.x;
    int rc = blockIdx.x >> 2;   // 0..63 (64-row chunk)
    int cb = blockIdx.x & 3;
    int r0 = rc * 64;
    int h0 = r0 >> 7;           // head owning these rows
    int dbase = r0 & 127;       // 0 or 64
    if (tid < 64) {             // combine: reconstruct attn rows [r0, r0+64)
        int d = dbase + tid;
        float M = -INFINITY;
#pragma unroll
        for (int c = 0; c < NCHUNK; ++c) M = fmaxf(M, part_m[h0 * NCHUNK + c]);
        float L = 0.f, O = 0.f;
#pragma unroll
        for (int c = 0; c < NCHUNK; ++c) {
            float f = __expf(part_m[h0 * NCHUNK + c] - M);
            L += f * part_l[h0 * NCHUNK + c];
            O += f * part_o[(size_t)(h0 * NCHUNK + c) * 128 + d];
        }
        xs[tid] = O / L;
    }
    __syncthreads();
    int col = cb * 1024 + tid * 4;
    const float* Wp = Wo + (size_t)r0 * 4096 + col;
    float4 acc = {0.f, 0.f, 0.f, 0.f};
#pragma unroll 8
    for (int r = 0; r < 64; ++r) {
        float4 w4 = *(const float4*)(Wp + (size_t)r * 4096);
        float xr = xs[r];
        acc.x = fmaf(xr, w4.x, acc.x);
        acc.y = fmaf(xr, w4.y, acc.y);
        acc.z = fmaf(xr, w4.z, acc.z);
        acc.w = fmaf(xr, w4.w, acc.w);
    }
    *(float4*)(wpart + (size_t)rc * 4096 + col) = acc;
}

// ---------- 5b. Output projection stage 2: reduce 64 partials -> out ----------
__global__ void wo2_kernel(const float* __restrict__ wpart,
                           float* __restrict__ out) {
    int tid = threadIdx.x;
    int col = blockIdx.x * 1024 + tid * 4;
    float4 acc = {0.f, 0.f, 0.f, 0.f};
#pragma unroll 8
    for (int rc = 0; rc < 64; ++rc) {
        float4 p = *(const float4*)(wpart + (size_t)rc * 4096 + col);
        acc.x += p.x; acc.y += p.y; acc.z += p.z; acc.w += p.w;
    }
    *(float4*)(out + col) = acc;
}

extern "C" void kernel_launch(void* const* d_in, const int* in_sizes, int n_in,
                              void* d_out, int out_size, void* d_ws, size_t ws_size,
                              hipStream_t stream) {
    const float* x  = (const float*)d_in[0];
    const float* kc = (const float*)d_in[1];
    const float* vc = (const float*)d_in[2];
    const float* Wq = (const float*)d_in[3];
    const float* Wk = (const float*)d_in[4];
    const float* Wv = (const float*)d_in[5];
    const float* Wo = (const float*)d_in[6];
    float* ws = (float*)d_ws;
    float* out = (float*)d_out;

    qkv1_kernel<<<384, 256, 0, stream>>>(x, Wq, Wk, Wv, ws + WS_QKVPART);
    reduce_rope_kernel<<<24, 256, 0, stream>>>(ws + WS_QKVPART, ws + WS_Q);
    score_kernel<<<(NPAGES - 1) * 2, 256, 0, stream>>>(kc, ws + WS_Q, ws + WS_SCORES);
    topk_kernel<<<H, 256, 0, stream>>>(ws + WS_SCORES, (int*)(ws + WS_PIDX));
    attn_kernel<<<H * NCHUNK, 256, 0, stream>>>(kc, vc, ws, (const int*)(ws + WS_PIDX),
                                                ws + WS_PART_M, ws + WS_PART_L, ws + WS_PART_O);
    wo1_kernel<<<256, 256, 0, stream>>>(ws + WS_PART_M, ws + WS_PART_L, ws + WS_PART_O,
                                        Wo, ws + WS_WOPART);
    wo2_kernel<<<4, 256, 0, stream>>>(ws + WS_WOPART, out);
}